// Round 1
// baseline (1112.519 us; speedup 1.0000x reference)
//
#include <hip/hip_runtime.h>
#include <hip/hip_bf16.h>

#define NPTS 50000
#define INDIM 16
#define NH 4
#define NC 64
#define HCD 256   // NH*NC
#define NEG 0.2f

typedef unsigned short u16;
typedef unsigned int   u32;
typedef __bf16 bf16x8 __attribute__((ext_vector_type(8)));
typedef float  f32x4  __attribute__((ext_vector_type(4)));

__device__ __forceinline__ float bf2f(u16 u){ return __uint_as_float(((u32)u) << 16); }
__device__ __forceinline__ u16 f2bf(float f){
  u32 w = __float_as_uint(f);
  u32 r = (w + 0x7fffu + ((w >> 16) & 1u)) >> 16;
  return (u16)r;
}

// ---------------- dtype detection ----------------
// Writes flag=1 if float buffers are f32, flag=0 if packed bf16.
__global__ void k_detect(const void* x, int* flag){
  if (threadIdx.x == 0 && blockIdx.x == 0){
    const u16* p = (const u16*)x;
    int zeros_even = 0, sane = 0;
    for (int t = 0; t < 512; t++){
      u16 u = p[t];
      if ((t & 1) == 0 && u == 0) zeros_even++;
      float a = fabsf(bf2f(u));
      if (u == 0 || (a > 0.015625f && a < 64.0f)) sane++;
    }
    int isf32;
    if (zeros_even > 200) isf32 = 1;       // f32 words holding bf16-rounded values
    else if (sane > 460)  isf32 = 0;       // genuine packed bf16 stream
    else                  isf32 = 1;       // full-precision f32
    *flag = isf32;
  }
}

// ---------------- canonicalize all float inputs to bf16 in ws ----------------
struct CvtArgs {
  const void* src[11];
  void*       dst[11];
  int         cnt[11];
};

__global__ void k_convert(CvtArgs a, const int* flag){
  int isf32 = *flag;
  long tid = (long)blockIdx.x * blockDim.x + threadIdx.x;
  long stride = (long)gridDim.x * blockDim.x;
  for (int s = 0; s < 11; s++){
    int n = a.cnt[s];
    const float* sf = (const float*)a.src[s];
    const u16*   sb = (const u16*)a.src[s];
    u16* d = (u16*)a.dst[s];
    for (long i = tid; i < n; i += stride){
      float v = isf32 ? sf[i] : bf2f(sb[i]);
      d[i] = f2bf(v);
    }
  }
}

// ---------------- layer-1 linear (K=16) + fused alpha reduce ----------------
// block = 256 threads handles 4 nodes; thread c = output column.
__global__ __launch_bounds__(256) void k_lin1(const u16* xb, const u16* W1b,
                                              const u16* a1s, const u16* a1d,
                                              u16* h, float* aS, float* aD, int kb){
  __shared__ float Wl[INDIM * HCD];   // 16 KB
  __shared__ float xl[4 * INDIM];
  int c = threadIdx.x;
  int i0 = blockIdx.x * 4;
  for (int t = c; t < INDIM * HCD; t += 256) Wl[t] = bf2f(W1b[kb * INDIM * HCD + t]);
  if (c < 4 * INDIM){
    int r = c >> 4, kk = c & 15;
    xl[c] = bf2f(xb[(long)(i0 + r) * INDIM + kk]);
  }
  __syncthreads();
  float as_w = bf2f(a1s[kb * HCD + c]);
  float ad_w = bf2f(a1d[kb * HCD + c]);
  int head = c >> 6, lane = c & 63;
  for (int r = 0; r < 4; r++){
    int node = i0 + r;
    float acc = 0.f;
    #pragma unroll
    for (int kk = 0; kk < INDIM; kk++) acc += xl[r * INDIM + kk] * Wl[kk * HCD + c];
    h[(long)node * HCD + c] = f2bf(acc);
    float s = acc * as_w, d = acc * ad_w;
    #pragma unroll
    for (int m = 32; m > 0; m >>= 1){ s += __shfl_xor(s, m, 64); d += __shfl_xor(d, m, 64); }
    if (lane == 0){ aS[node * NH + head] = s; aD[node * NH + head] = d; }
  }
}

// ---------------- neighbor stencils ----------------
template<int BRANCH> struct Nbr;
template<> struct Nbr<0>{ static constexpr int CNT = 7;  };
template<> struct Nbr<1>{ static constexpr int CNT = 7;  };
template<> struct Nbr<2>{ static constexpr int CNT = 13; };

template<int BRANCH>
__device__ __forceinline__ int nbr_off(int t){
  if (BRANCH == 0){ constexpr int O[7]  = {0,-1,-3,-5,-7,-9,-11}; return O[t]; }
  else if (BRANCH == 1){ constexpr int O[7]  = {0,1,3,5,7,9,11}; return O[t]; }
  else { constexpr int O[13] = {0,-1,1,-3,3,-5,5,-7,7,-9,9,-11,11}; return O[t]; }
}

// softmax-weighted stencil aggregation for one (node i, flat column c)
template<int BRANCH>
__device__ __forceinline__ float gat_agg(const u16* hmat, const float* aS, const float* aD,
                                         int i, int c, int head){
  constexpr int CNT = Nbr<BRANCH>::CNT;
  float ad = aD[i * NH + head];
  float e[CNT];
  float emax = -3e38f;
  #pragma unroll
  for (int t = 0; t < CNT; t++){
    int j = i + nbr_off<BRANCH>(t);
    bool ok = (j >= 0) && (j < NPTS);
    float v = ok ? (aS[j * NH + head] + ad) : -3e38f;
    v = v > 0.f ? v : NEG * v;
    e[t] = v;
    emax = fmaxf(emax, v);
  }
  float den = 0.f;
  #pragma unroll
  for (int t = 0; t < CNT; t++){ float xv = expf(e[t] - emax); e[t] = xv; den += xv; }
  float inv = 1.f / den;
  float acc = 0.f;
  #pragma unroll
  for (int t = 0; t < CNT; t++){
    int j = i + nbr_off<BRANCH>(t);
    int jc = j < 0 ? 0 : (j >= NPTS ? NPTS - 1 : j);
    acc += e[t] * bf2f(hmat[(long)jc * HCD + c]);
  }
  return acc * inv;
}

// layer-1 aggregation (concat) + bias -> x2
template<int BRANCH>
__global__ __launch_bounds__(256) void k_agg1(const u16* h, const float* aS, const float* aD,
                                              const u16* b1b, u16* x2, int kb){
  int c = threadIdx.x, i = blockIdx.x, head = c >> 6;
  float acc = gat_agg<BRANCH>(h, aS, aD, i, c, head);
  x2[(long)i * HCD + c] = f2bf(acc + bf2f(b1b[kb * HCD + c]));
}

// ---------------- layer-2 linear: MFMA GEMM [N,256]x[256,256] ----------------
// grid (3125, 16), 64 threads/block. 16x16 output tile, K-loop of 8.
__global__ __launch_bounds__(64) void k_lin2(const u16* x2, const u16* W2b, u16* h2, int kb){
  int l = threadIdx.x;
  int r0 = blockIdx.x * 16, c0 = blockIdx.y * 16;
  int lm = l & 15, lg = l >> 4;
  const __bf16* W2p = (const __bf16*)(W2b + (long)kb * HCD * HCD);
  f32x4 acc = {0.f, 0.f, 0.f, 0.f};
  for (int k0 = 0; k0 < HCD; k0 += 32){
    bf16x8 a = *(const bf16x8*)(x2 + (long)(r0 + lm) * HCD + k0 + lg * 8);
    bf16x8 b;
    #pragma unroll
    for (int j = 0; j < 8; j++) b[j] = W2p[(long)(k0 + lg * 8 + j) * HCD + c0 + lm];
    acc = __builtin_amdgcn_mfma_f32_16x16x32_bf16(a, b, acc, 0, 0, 0);
  }
  #pragma unroll
  for (int r = 0; r < 4; r++){
    int row = r0 + lg * 4 + r;
    h2[(long)row * HCD + c0 + lm] = f2bf(acc[r]);
  }
}

// ---------------- layer-2 alpha ----------------
__global__ __launch_bounds__(256) void k_alpha2(const u16* h2, const u16* a2s, const u16* a2d,
                                                float* aS, float* aD, int kb){
  int c = threadIdx.x, i = blockIdx.x;
  int head = c >> 6, lane = c & 63;
  float v = bf2f(h2[(long)i * HCD + c]);
  float s = v * bf2f(a2s[kb * HCD + c]);
  float d = v * bf2f(a2d[kb * HCD + c]);
  #pragma unroll
  for (int m = 32; m > 0; m >>= 1){ s += __shfl_xor(s, m, 64); d += __shfl_xor(d, m, 64); }
  if (lane == 0){ aS[i * NH + head] = s; aD[i * NH + head] = d; }
}

// ---------------- layer-2 aggregation (mean heads) + bias + fc ----------------
template<int BRANCH>
__global__ __launch_bounds__(256) void k_agg2fc(const u16* h2, const float* aS, const float* aD,
                                                const u16* b2b, const u16* wfcb, const u16* bfcb,
                                                void* out, const int* flag, int kb){
  __shared__ float red[HCD];
  int c = threadIdx.x, i = blockIdx.x, head = c >> 6;
  float acc = gat_agg<BRANCH>(h2, aS, aD, i, c, head);
  red[c] = acc;
  __syncthreads();
  if (c < NC){
    float x3 = (red[c] + red[c + 64] + red[c + 128] + red[c + 192]) * 0.25f + bf2f(b2b[kb * NC + c]);
    float p = x3 * bf2f(wfcb[kb * NC + c]);
    #pragma unroll
    for (int m = 32; m > 0; m >>= 1) p += __shfl_xor(p, m, 64);
    if (c == 0){
      float o = p + bf2f(bfcb[kb]);
      long oi = (long)kb * NPTS + i;
      if (*flag) ((float*)out)[oi] = o;
      else       ((u16*)out)[oi]  = f2bf(o);
    }
  }
}

extern "C" void kernel_launch(void* const* d_in, const int* in_sizes, int n_in,
                              void* d_out, int out_size, void* d_ws, size_t ws_size,
                              hipStream_t stream){
  char* ws = (char*)d_ws;
  size_t off = 0;
  auto take = [&](size_t b) -> size_t { size_t r = off; off += (b + 255) & ~(size_t)255; return r; };

  int* flag = (int*)(ws + take(4));
  u16* xb   = (u16*)(ws + take((size_t)NPTS * INDIM * 2));
  u16* W1b  = (u16*)(ws + take((size_t)3 * INDIM * HCD * 2));
  u16* a1s  = (u16*)(ws + take((size_t)3 * HCD * 2));
  u16* a1d  = (u16*)(ws + take((size_t)3 * HCD * 2));
  u16* b1b  = (u16*)(ws + take((size_t)3 * HCD * 2));
  u16* W2b  = (u16*)(ws + take((size_t)3 * HCD * HCD * 2));
  u16* a2s  = (u16*)(ws + take((size_t)3 * HCD * 2));
  u16* a2d  = (u16*)(ws + take((size_t)3 * HCD * 2));
  u16* b2b  = (u16*)(ws + take((size_t)3 * NC * 2));
  u16* wfcb = (u16*)(ws + take((size_t)3 * NC * 2));
  u16* bfcb = (u16*)(ws + take((size_t)3 * 2));
  u16* hbuf = (u16*)(ws + take((size_t)NPTS * HCD * 2));   // h1, reused as h2
  u16* x2   = (u16*)(ws + take((size_t)NPTS * HCD * 2));
  float* aS = (float*)(ws + take((size_t)NPTS * NH * 4));
  float* aD = (float*)(ws + take((size_t)NPTS * NH * 4));

  k_detect<<<1, 64, 0, stream>>>(d_in[0], flag);

  CvtArgs ca;
  const int srcidx[11] = {0, 4, 5, 6, 7, 8, 9, 10, 11, 12, 13};
  void* dsts[11] = {xb, W1b, a1s, a1d, b1b, W2b, a2s, a2d, b2b, wfcb, bfcb};
  const int cnts[11] = {NPTS * INDIM, 3 * INDIM * HCD, 3 * HCD, 3 * HCD, 3 * HCD,
                        3 * HCD * HCD, 3 * HCD, 3 * HCD, 3 * NC, 3 * NC, 3};
  for (int s = 0; s < 11; s++){ ca.src[s] = d_in[srcidx[s]]; ca.dst[s] = dsts[s]; ca.cnt[s] = cnts[s]; }
  k_convert<<<512, 256, 0, stream>>>(ca, flag);

  for (int kb = 0; kb < 3; kb++){
    k_lin1<<<NPTS / 4, 256, 0, stream>>>(xb, W1b, a1s, a1d, hbuf, aS, aD, kb);
    if      (kb == 0) k_agg1<0><<<NPTS, 256, 0, stream>>>(hbuf, aS, aD, b1b, x2, kb);
    else if (kb == 1) k_agg1<1><<<NPTS, 256, 0, stream>>>(hbuf, aS, aD, b1b, x2, kb);
    else              k_agg1<2><<<NPTS, 256, 0, stream>>>(hbuf, aS, aD, b1b, x2, kb);
    k_lin2<<<dim3(NPTS / 16, HCD / 16), 64, 0, stream>>>(x2, W2b, hbuf, kb);
    k_alpha2<<<NPTS, 256, 0, stream>>>(hbuf, a2s, a2d, aS, aD, kb);
    if      (kb == 0) k_agg2fc<0><<<NPTS, 256, 0, stream>>>(hbuf, aS, aD, b2b, wfcb, bfcb, d_out, flag, kb);
    else if (kb == 1) k_agg2fc<1><<<NPTS, 256, 0, stream>>>(hbuf, aS, aD, b2b, wfcb, bfcb, d_out, flag, kb);
    else              k_agg2fc<2><<<NPTS, 256, 0, stream>>>(hbuf, aS, aD, b2b, wfcb, bfcb, d_out, flag, kb);
  }
}

// Round 2
// 609.683 us; speedup vs baseline: 1.8247x; 1.8247x over previous
//
#include <hip/hip_runtime.h>
#include <hip/hip_bf16.h>

#define NPTS 50000
#define INDIM 16
#define NH 4
#define NC 64
#define HCD 256   // NH*NC
#define NEG 0.2f

typedef unsigned short u16;
typedef unsigned int   u32;
typedef __bf16 bf16x8 __attribute__((ext_vector_type(8)));
typedef float  f32x4  __attribute__((ext_vector_type(4)));

__device__ __forceinline__ float bf2f(u16 u){ return __uint_as_float(((u32)u) << 16); }
__device__ __forceinline__ u16 f2bf(float f){
  u32 w = __float_as_uint(f);
  u32 r = (w + 0x7fffu + ((w >> 16) & 1u)) >> 16;
  return (u16)r;
}

// ---------------- dtype detection ----------------
__global__ void k_detect(const void* x, int* flag){
  if (threadIdx.x == 0 && blockIdx.x == 0){
    const u16* p = (const u16*)x;
    int zeros_even = 0, sane = 0;
    for (int t = 0; t < 512; t++){
      u16 u = p[t];
      if ((t & 1) == 0 && u == 0) zeros_even++;
      float a = fabsf(bf2f(u));
      if (u == 0 || (a > 0.015625f && a < 64.0f)) sane++;
    }
    int isf32;
    if (zeros_even > 200) isf32 = 1;
    else if (sane > 460)  isf32 = 0;
    else                  isf32 = 1;
    *flag = isf32;
  }
}

// ---------------- canonicalize float inputs to bf16 in ws ----------------
struct CvtArgs {
  const void* src[11];
  void*       dst[11];
  int         cnt[11];
};

__global__ void k_convert(CvtArgs a, const int* flag){
  int isf32 = *flag;
  long tid = (long)blockIdx.x * blockDim.x + threadIdx.x;
  long stride = (long)gridDim.x * blockDim.x;
  for (int s = 0; s < 11; s++){
    int n = a.cnt[s];
    const float* sf = (const float*)a.src[s];
    const u16*   sb = (const u16*)a.src[s];
    u16* d = (u16*)a.dst[s];
    for (long i = tid; i < n; i += stride){
      float v = isf32 ? sf[i] : bf2f(sb[i]);
      d[i] = f2bf(v);
    }
  }
}

// ---------------- prep: fold a1 vectors through W1 ----------------
// Ws1[(kb*NH+head)*16 + k] = sum_ch W1[kb][k][head*64+ch] * a1s[kb][head*64+ch]
__global__ void k_prep(const u16* W1b, const u16* a1s, const u16* a1d,
                       float* Ws1, float* Wd1){
  int bid = blockIdx.x;              // 3*4*16 = 192 blocks
  int kb = bid >> 6, rem = bid & 63;
  int head = rem >> 4, k = rem & 15;
  int ch = threadIdx.x;              // 64 threads
  int col = head * 64 + ch;
  float w = bf2f(W1b[kb * INDIM * HCD + k * HCD + col]);
  float s = w * bf2f(a1s[kb * HCD + col]);
  float d = w * bf2f(a1d[kb * HCD + col]);
  #pragma unroll
  for (int m = 32; m > 0; m >>= 1){ s += __shfl_xor(s, m, 64); d += __shfl_xor(d, m, 64); }
  if (ch == 0){
    Ws1[(kb * NH + head) * INDIM + k] = s;
    Wd1[(kb * NH + head) * INDIM + k] = d;
  }
}

// ---------------- transpose W2 -> W2T[c][k] ----------------
__global__ void k_transpose(const u16* W2b, u16* W2T){
  int kb = blockIdx.y, k = blockIdx.x, c = threadIdx.x;
  long base = (long)kb * HCD * HCD;
  W2T[base + (long)c * HCD + k] = W2b[base + (long)k * HCD + c];
}

// ---------------- layer-1 linear (K=16): pure GEMM ----------------
// block 256, grid 6250: 8 nodes/block, thread = output column
__global__ __launch_bounds__(256) void k_lin1(const u16* xb, const u16* W1b, u16* h, int kb){
  __shared__ float xl[8 * INDIM];
  int c = threadIdx.x;
  int i0 = blockIdx.x * 8;
  if (c < 8 * INDIM) xl[c] = bf2f(xb[(long)i0 * INDIM + c]);
  float w[INDIM];
  #pragma unroll
  for (int k = 0; k < INDIM; k++) w[k] = bf2f(W1b[kb * INDIM * HCD + k * HCD + c]);
  __syncthreads();
  #pragma unroll
  for (int r = 0; r < 8; r++){
    float acc = 0.f;
    #pragma unroll
    for (int k = 0; k < INDIM; k++) acc += xl[r * INDIM + k] * w[k];
    h[(long)(i0 + r) * HCD + c] = f2bf(acc);
  }
}

// ---------------- layer-1 alpha via folded vectors ----------------
__global__ __launch_bounds__(256) void k_alpha1(const u16* xb, const float* Ws1, const float* Wd1,
                                                float* aS, float* aD, int kb){
  int idx = blockIdx.x * 256 + threadIdx.x;
  if (idx >= NPTS * NH) return;
  int node = idx >> 2, head = idx & 3;
  const float* ws = Ws1 + (kb * NH + head) * INDIM;
  const float* wd = Wd1 + (kb * NH + head) * INDIM;
  float s = 0.f, d = 0.f;
  #pragma unroll
  for (int k = 0; k < INDIM; k++){
    float xv = bf2f(xb[(long)node * INDIM + k]);
    s += xv * ws[k]; d += xv * wd[k];
  }
  aS[idx] = s; aD[idx] = d;   // idx == node*NH + head
}

// ---------------- neighbor stencils ----------------
template<int BRANCH> struct Nbr;
template<> struct Nbr<0>{ static constexpr int CNT = 7;  };
template<> struct Nbr<1>{ static constexpr int CNT = 7;  };
template<> struct Nbr<2>{ static constexpr int CNT = 13; };

template<int BRANCH>
__device__ __forceinline__ int nbr_off(int t){
  if (BRANCH == 0){ constexpr int O[7]  = {0,-1,-3,-5,-7,-9,-11}; return O[t]; }
  else if (BRANCH == 1){ constexpr int O[7]  = {0,1,3,5,7,9,11}; return O[t]; }
  else { constexpr int O[13] = {0,-1,1,-3,3,-5,5,-7,7,-9,9,-11,11}; return O[t]; }
}

// wave-parallel softmax-weighted stencil aggregation for (node i, column c)
template<int BRANCH>
__device__ __forceinline__ float gat_agg(const u16* hmat, const float* aS, const float* aD,
                                         int i, int c, int head){
  constexpr int CNT = Nbr<BRANCH>::CNT;
  int lane = c & 63;
  // lanes 0..CNT-1 each compute one tap's logit
  float e = -3e38f;
  if (lane < CNT){
    int j = i + nbr_off<BRANCH>(lane);
    if (j >= 0 && j < NPTS){
      float v = aS[j * NH + head] + aD[i * NH + head];
      e = v > 0.f ? v : NEG * v;
    }
  }
  // full-wave max + sum reductions (inactive lanes carry -3e38 -> exp 0)
  float m = e;
  #pragma unroll
  for (int msk = 1; msk < 64; msk <<= 1) m = fmaxf(m, __shfl_xor(m, msk, 64));
  float ex = expf(e - m);
  float den = ex;
  #pragma unroll
  for (int msk = 1; msk < 64; msk <<= 1) den += __shfl_xor(den, msk, 64);
  float myw = ex / den;
  float acc = 0.f;
  #pragma unroll
  for (int t = 0; t < CNT; t++){
    float w = __shfl(myw, t, 64);
    int j = i + nbr_off<BRANCH>(t);
    int jc = j < 0 ? 0 : (j >= NPTS ? NPTS - 1 : j);   // w==0 there anyway
    acc += w * bf2f(hmat[(long)jc * HCD + c]);
  }
  return acc;
}

// layer-1 aggregation (concat) + bias -> x2
template<int BRANCH>
__global__ __launch_bounds__(256) void k_agg1(const u16* h, const float* aS, const float* aD,
                                              const u16* b1b, u16* x2, int kb){
  int c = threadIdx.x, i = blockIdx.x, head = c >> 6;
  float acc = gat_agg<BRANCH>(h, aS, aD, i, c, head);
  x2[(long)i * HCD + c] = f2bf(acc + bf2f(b1b[kb * HCD + c]));
}

// ---------------- layer-2 linear: MFMA GEMM + fused alpha2 ----------------
// grid 3125, 256 threads = 4 waves; block = 16 rows x 256 cols; wave w = head w
__global__ __launch_bounds__(256) void k_lin2(const u16* x2, const u16* W2T, u16* h2,
                                              const u16* a2s, const u16* a2d,
                                              float* aS, float* aD, int kb){
  int wv = threadIdx.x >> 6, l = threadIdx.x & 63;
  int lm = l & 15, lg = l >> 4;
  int r0 = blockIdx.x * 16;
  const u16* W2p = W2T + (long)kb * HCD * HCD;
  f32x4 acc[4] = {{0,0,0,0},{0,0,0,0},{0,0,0,0},{0,0,0,0}};
  for (int k0 = 0; k0 < HCD; k0 += 32){
    bf16x8 a = *(const bf16x8*)(x2 + (long)(r0 + lm) * HCD + k0 + lg * 8);
    #pragma unroll
    for (int n = 0; n < 4; n++){
      int col = wv * 64 + n * 16 + lm;
      bf16x8 b = *(const bf16x8*)(W2p + (long)col * HCD + k0 + lg * 8);
      acc[n] = __builtin_amdgcn_mfma_f32_16x16x32_bf16(a, b, acc[n], 0, 0, 0);
    }
  }
  // store h2 (bf16)
  #pragma unroll
  for (int n = 0; n < 4; n++){
    #pragma unroll
    for (int r = 0; r < 4; r++){
      int row = r0 + lg * 4 + r;
      h2[(long)row * HCD + wv * 64 + n * 16 + lm] = f2bf(acc[n][r]);
    }
  }
  // fused alpha2: per row, dot over this wave's (= head wv's) 64 cols
  float a2s_v[4], a2d_v[4];
  #pragma unroll
  for (int n = 0; n < 4; n++){
    int col = wv * 64 + n * 16 + lm;
    a2s_v[n] = bf2f(a2s[kb * HCD + col]);
    a2d_v[n] = bf2f(a2d[kb * HCD + col]);
  }
  #pragma unroll
  for (int r = 0; r < 4; r++){
    float s = 0.f, d = 0.f;
    #pragma unroll
    for (int n = 0; n < 4; n++){ float v = acc[n][r]; s += v * a2s_v[n]; d += v * a2d_v[n]; }
    #pragma unroll
    for (int msk = 1; msk < 16; msk <<= 1){ s += __shfl_xor(s, msk, 64); d += __shfl_xor(d, msk, 64); }
    if (lm == 0){
      int row = r0 + lg * 4 + r;
      aS[row * NH + wv] = s;
      aD[row * NH + wv] = d;
    }
  }
}

// ---------------- layer-2 aggregation (mean heads) + bias + fc ----------------
template<int BRANCH>
__global__ __launch_bounds__(256) void k_agg2fc(const u16* h2, const float* aS, const float* aD,
                                                const u16* b2b, const u16* wfcb, const u16* bfcb,
                                                void* out, const int* flag, int kb){
  __shared__ float red[HCD];
  int c = threadIdx.x, i = blockIdx.x, head = c >> 6;
  float acc = gat_agg<BRANCH>(h2, aS, aD, i, c, head);
  red[c] = acc;
  __syncthreads();
  if (c < NC){
    float x3 = (red[c] + red[c + 64] + red[c + 128] + red[c + 192]) * 0.25f + bf2f(b2b[kb * NC + c]);
    float p = x3 * bf2f(wfcb[kb * NC + c]);
    #pragma unroll
    for (int m = 32; m > 0; m >>= 1) p += __shfl_xor(p, m, 64);
    if (c == 0){
      float o = p + bf2f(bfcb[kb]);
      long oi = (long)kb * NPTS + i;
      if (*flag) ((float*)out)[oi] = o;
      else       ((u16*)out)[oi]  = f2bf(o);
    }
  }
}

extern "C" void kernel_launch(void* const* d_in, const int* in_sizes, int n_in,
                              void* d_out, int out_size, void* d_ws, size_t ws_size,
                              hipStream_t stream){
  char* ws = (char*)d_ws;
  size_t off = 0;
  auto take = [&](size_t b) -> size_t { size_t r = off; off += (b + 255) & ~(size_t)255; return r; };

  int* flag = (int*)(ws + take(4));
  u16* xb   = (u16*)(ws + take((size_t)NPTS * INDIM * 2));
  u16* W1b  = (u16*)(ws + take((size_t)3 * INDIM * HCD * 2));
  u16* a1s  = (u16*)(ws + take((size_t)3 * HCD * 2));
  u16* a1d  = (u16*)(ws + take((size_t)3 * HCD * 2));
  u16* b1b  = (u16*)(ws + take((size_t)3 * HCD * 2));
  u16* W2b  = (u16*)(ws + take((size_t)3 * HCD * HCD * 2));
  u16* a2s  = (u16*)(ws + take((size_t)3 * HCD * 2));
  u16* a2d  = (u16*)(ws + take((size_t)3 * HCD * 2));
  u16* b2b  = (u16*)(ws + take((size_t)3 * NC * 2));
  u16* wfcb = (u16*)(ws + take((size_t)3 * NC * 2));
  u16* bfcb = (u16*)(ws + take((size_t)3 * 2));
  u16* W2T  = (u16*)(ws + take((size_t)3 * HCD * HCD * 2));
  float* Ws1 = (float*)(ws + take((size_t)3 * NH * INDIM * 4));
  float* Wd1 = (float*)(ws + take((size_t)3 * NH * INDIM * 4));
  u16* hbuf = (u16*)(ws + take((size_t)NPTS * HCD * 2));   // h1, reused as h2
  u16* x2   = (u16*)(ws + take((size_t)NPTS * HCD * 2));
  float* aS = (float*)(ws + take((size_t)NPTS * NH * 4));
  float* aD = (float*)(ws + take((size_t)NPTS * NH * 4));

  k_detect<<<1, 64, 0, stream>>>(d_in[0], flag);

  CvtArgs ca;
  const int srcidx[11] = {0, 4, 5, 6, 7, 8, 9, 10, 11, 12, 13};
  void* dsts[11] = {xb, W1b, a1s, a1d, b1b, W2b, a2s, a2d, b2b, wfcb, bfcb};
  const int cnts[11] = {NPTS * INDIM, 3 * INDIM * HCD, 3 * HCD, 3 * HCD, 3 * HCD,
                        3 * HCD * HCD, 3 * HCD, 3 * HCD, 3 * NC, 3 * NC, 3};
  for (int s = 0; s < 11; s++){ ca.src[s] = d_in[srcidx[s]]; ca.dst[s] = dsts[s]; ca.cnt[s] = cnts[s]; }
  k_convert<<<512, 256, 0, stream>>>(ca, flag);

  k_prep<<<192, 64, 0, stream>>>(W1b, a1s, a1d, Ws1, Wd1);
  k_transpose<<<dim3(HCD, 3), HCD, 0, stream>>>(W2b, W2T);

  for (int kb = 0; kb < 3; kb++){
    k_lin1<<<NPTS / 8, 256, 0, stream>>>(xb, W1b, hbuf, kb);
    k_alpha1<<<(NPTS * NH + 255) / 256, 256, 0, stream>>>(xb, Ws1, Wd1, aS, aD, kb);
    if      (kb == 0) k_agg1<0><<<NPTS, 256, 0, stream>>>(hbuf, aS, aD, b1b, x2, kb);
    else if (kb == 1) k_agg1<1><<<NPTS, 256, 0, stream>>>(hbuf, aS, aD, b1b, x2, kb);
    else              k_agg1<2><<<NPTS, 256, 0, stream>>>(hbuf, aS, aD, b1b, x2, kb);
    k_lin2<<<NPTS / 16, 256, 0, stream>>>(x2, W2T, hbuf, a2s, a2d, aS, aD, kb);
    if      (kb == 0) k_agg2fc<0><<<NPTS, 256, 0, stream>>>(hbuf, aS, aD, b2b, wfcb, bfcb, d_out, flag, kb);
    else if (kb == 1) k_agg2fc<1><<<NPTS, 256, 0, stream>>>(hbuf, aS, aD, b2b, wfcb, bfcb, d_out, flag, kb);
    else              k_agg2fc<2><<<NPTS, 256, 0, stream>>>(hbuf, aS, aD, b2b, wfcb, bfcb, d_out, flag, kb);
  }
}

// Round 4
// 127.588 us; speedup vs baseline: 8.7196x; 4.7785x over previous
//
#include <hip/hip_runtime.h>
#include <hip/hip_bf16.h>

#define NPTS 50000
#define SA (NPTS * 4)         // per-branch (node,head) array size
#define NEG 0.2f
#define PSTRIDE 960           // folded-param floats per branch (909 used)

typedef unsigned short u16;
typedef unsigned int   u32;

__device__ __forceinline__ float bf2f(u16 u){ return __uint_as_float(((u32)u) << 16); }
__device__ __forceinline__ u16 f2bf(float f){
  u32 w = __float_as_uint(f);
  return (u16)((w + 0x7fffu + ((w >> 16) & 1u)) >> 16);
}
__device__ __forceinline__ float ldraw(const void* p, long i, int isf32){
  return isf32 ? ((const float*)p)[i] : bf2f(((const u16*)p)[i]);
}

// wave-parallel dtype sniff on first 512 u16 of x
__device__ int detect_isf32(const void* x){
  int lane = threadIdx.x & 63;
  const u16* p = (const u16*)x;
  int ze = 0, sane = 0;
  #pragma unroll
  for (int r = 0; r < 8; r++){
    int idx = lane * 8 + r;
    u16 u = p[idx];
    if ((idx & 1) == 0 && u == 0) ze++;
    float a = fabsf(bf2f(u));
    if (u == 0 || (a > 0.015625f && a < 64.f)) sane++;
  }
  #pragma unroll
  for (int m = 32; m > 0; m >>= 1){ ze += __shfl_xor(ze, m, 64); sane += __shfl_xor(sane, m, 64); }
  return (ze > 200) ? 1 : (sane > 460 ? 0 : 1);
}

// stencil offsets per branch (padded to 13)
__device__ const int g_off[48] = {
  0,-1,-3,-5,-7,-9,-11, 0, 0, 0, 0, 0, 0, 0, 0, 0,
  0, 1, 3, 5, 7, 9, 11, 0, 0, 0, 0, 0, 0, 0, 0, 0,
  0,-1, 1,-3, 3,-5, 5,-7, 7,-9, 9,-11,11, 0, 0, 0};
__device__ const int g_cnt[3] = {7, 7, 13};

// ---------------- fold all weights into per-branch params P ----------------
// P[0:64)    Ws1[k*4+h]        alpha1_src = x . Ws1
// P[64:128)  Wd1[k*4+h]
// P[128:384) Ws2[k*16+h*4+h']  gs[i,h,h'] = x . Ws2   (h = L1 head, h' = L2 head)
// P[384:640) Wd2[k*16+h*4+h']
// P[640:896) Wf2[k*16+h*4+h']
// P[896+h'] c2s, [900+h'] c2d, [904+h'] c2f, [908] Cb
__global__ __launch_bounds__(256) void k_folds(const void* x, const void* W1, const void* a1s,
                                               const void* a1d, const void* b1, const void* W2,
                                               const void* a2s, const void* a2d, const void* b2,
                                               const void* wfc, const void* bfc, float* P){
  __shared__ float sA[3][256][4];   // A2S/A2D/AF: W2 row m folded per L2-head h'
  __shared__ int s_flag;
  int kb = blockIdx.y;
  int tid = threadIdx.x;
  if (tid < 64){ int f = detect_isf32(x); if (tid == 0) s_flag = f; }
  __syncthreads();
  int isf32 = s_flag;

  { // phase 1: A2*[m][h'] = sum_c' W2[m, h'*64+c'] * vec[c']
    int m = tid;
    long w2base = (long)kb * 65536 + (long)m * 256;
    #pragma unroll
    for (int hp = 0; hp < 4; hp++){
      float s = 0.f, d = 0.f, f = 0.f;
      for (int ch = 0; ch < 64; ch++){
        int c = hp * 64 + ch;
        float w = ldraw(W2, w2base + c, isf32);
        s += w * ldraw(a2s, kb * 256 + c, isf32);
        d += w * ldraw(a2d, kb * 256 + c, isf32);
        f += w * ldraw(wfc, kb * 64 + ch, isf32) * 0.25f;
      }
      sA[0][m][hp] = s; sA[1][m][hp] = d; sA[2][m][hp] = f;
    }
  }
  __syncthreads();
  float* Pp = P + kb * PSTRIDE;

  { // phase 2a: Ws2/Wd2/Wf2[k][h][h'] = sum_{c in head h} W1[k, h*64+c] * A2*[h*64+c][h']
    int k = tid >> 4, h = (tid >> 2) & 3, hp = tid & 3;
    long w1base = (long)kb * 4096 + (long)k * 256;
    float s = 0.f, d = 0.f, f = 0.f;
    for (int ch = 0; ch < 64; ch++){
      int m = h * 64 + ch;
      float w = ldraw(W1, w1base + m, isf32);
      s += w * sA[0][m][hp];
      d += w * sA[1][m][hp];
      f += w * sA[2][m][hp];
    }
    Pp[128 + tid] = s; Pp[384 + tid] = d; Pp[640 + tid] = f;
  }

  if (tid < 64){ // phase 2b: Ws1/Wd1[k][h]
    int k = tid >> 2, h = tid & 3;
    long w1base = (long)kb * 4096 + (long)k * 256;
    float s1 = 0.f, d1 = 0.f;
    for (int ch = 0; ch < 64; ch++){
      int c = h * 64 + ch;
      float w = ldraw(W1, w1base + c, isf32);
      s1 += w * ldraw(a1s, kb * 256 + c, isf32);
      d1 += w * ldraw(a1d, kb * 256 + c, isf32);
    }
    Pp[tid] = s1; Pp[64 + tid] = d1;
  } else if (tid < 76){ // biases: c2s/c2d/c2f[h'] = sum_m b1[m]*A2*[m][h']
    int j = tid - 64, q = j >> 2, hp = j & 3;
    float acc = 0.f;
    for (int m = 0; m < 256; m++) acc += ldraw(b1, kb * 256 + m, isf32) * sA[q][m][hp];
    Pp[896 + j] = acc;
  } else if (tid == 76){
    float acc = 0.f;
    for (int ch = 0; ch < 64; ch++) acc += ldraw(b2, kb * 64 + ch, isf32) * ldraw(wfc, kb * 64 + ch, isf32);
    Pp[908] = acc + ldraw(bfc, kb, isf32);
  }
}

// ---------------- per-node projections of x: 4+4+16+16+16 ----------------
__global__ __launch_bounds__(256) void k_feat(const void* x, const float* P,
                                              float* aS1, float* aD1,
                                              float* gs, float* gd, float* gf){
  __shared__ float sP[912];
  __shared__ int s_flag;
  int kb = blockIdx.y;
  if (threadIdx.x < 64){ int f = detect_isf32(x); if (threadIdx.x == 0) s_flag = f; }
  for (int i = threadIdx.x; i < 912; i += 256) sP[i] = P[kb * PSTRIDE + i];
  __syncthreads();
  int isf32 = s_flag;
  int node = blockIdx.x * 256 + threadIdx.x;
  if (node >= NPTS) return;

  float xv[16];
  if (isf32){
    const float4* xp = (const float4*)x + (long)node * 4;
    #pragma unroll
    for (int q = 0; q < 4; q++){
      float4 v = xp[q];
      xv[q*4] = v.x; xv[q*4+1] = v.y; xv[q*4+2] = v.z; xv[q*4+3] = v.w;
    }
  } else {
    const uint4* xp = (const uint4*)x + (long)node * 2;
    #pragma unroll
    for (int q = 0; q < 2; q++){
      uint4 v = xp[q];
      u32 wsv[4] = {v.x, v.y, v.z, v.w};
      #pragma unroll
      for (int r = 0; r < 4; r++){
        xv[q*8 + r*2]     = bf2f((u16)(wsv[r] & 0xffffu));
        xv[q*8 + r*2 + 1] = bf2f((u16)(wsv[r] >> 16));
      }
    }
  }

  float s1[4] = {0,0,0,0}, d1[4] = {0,0,0,0};
  float s2[16], d2[16], f2[16];
  #pragma unroll
  for (int t = 0; t < 16; t++){ s2[t] = 0.f; d2[t] = 0.f; f2[t] = 0.f; }
  #pragma unroll
  for (int k = 0; k < 16; k++){
    float xk = xv[k];
    #pragma unroll
    for (int h = 0; h < 4; h++){
      s1[h] += xk * sP[     k*4 + h];
      d1[h] += xk * sP[64 + k*4 + h];
    }
    #pragma unroll
    for (int t = 0; t < 16; t++){
      s2[t] += xk * sP[128 + k*16 + t];
      d2[t] += xk * sP[384 + k*16 + t];
      f2[t] += xk * sP[640 + k*16 + t];
    }
  }
  long ab = (long)kb * SA + (long)node * 4;
  *(float4*)&aS1[ab] = make_float4(s1[0], s1[1], s1[2], s1[3]);
  *(float4*)&aD1[ab] = make_float4(d1[0], d1[1], d1[2], d1[3]);
  long gb = ((long)kb * NPTS + node) * 16;
  #pragma unroll
  for (int q = 0; q < 4; q++){
    *(float4*)&gs[gb + q*4] = make_float4(s2[q*4], s2[q*4+1], s2[q*4+2], s2[q*4+3]);
    *(float4*)&gd[gb + q*4] = make_float4(d2[q*4], d2[q*4+1], d2[q*4+2], d2[q*4+3]);
    *(float4*)&gf[gb + q*4] = make_float4(f2[q*4], f2[q*4+1], f2[q*4+2], f2[q*4+3]);
  }
}

// ---------------- layer-1 softmax + stencil: thread per (node, L1-head h) ----------------
__global__ __launch_bounds__(256) void k_l2pre(const float* aS1, const float* aD1,
                                               const float* gs, const float* gd, const float* gf,
                                               const float* P, float* aS2, float* aD2, float* gf2){
  int t = blockIdx.x * 256 + threadIdx.x;
  int node = t >> 2, h = t & 3;
  if (node >= NPTS) return;
  int kb = blockIdx.y;
  long abase = (long)kb * SA;
  long gbase = (long)kb * NPTS * 16;
  float adv = aD1[abase + (long)node * 4 + h];
  int cnt = g_cnt[kb];

  float e[13]; int jc[13];
  float mx = -3e38f;
  #pragma unroll
  for (int tt = 0; tt < 13; tt++){
    int off = g_off[kb * 16 + tt];
    int j = node + off;
    bool ok = (tt < cnt) && ((unsigned)j < NPTS);
    int jj = j < 0 ? 0 : (j >= NPTS ? NPTS - 1 : j);
    jc[tt] = jj;
    float v = aS1[abase + (long)jj * 4 + h] + adv;
    v = v > 0.f ? v : NEG * v;
    e[tt] = ok ? v : -3e38f;
    mx = fmaxf(mx, e[tt]);
  }
  float den = 0.f;
  float ts[4] = {0,0,0,0}, td[4] = {0,0,0,0}, tf[4] = {0,0,0,0};
  #pragma unroll
  for (int tt = 0; tt < 13; tt++){
    float ex = expf(e[tt] - mx);
    den += ex;
    long gi = gbase + (long)jc[tt] * 16 + h * 4;
    float4 vs = *(const float4*)&gs[gi];
    float4 vd = *(const float4*)&gd[gi];
    float4 vf = *(const float4*)&gf[gi];
    ts[0] += ex * vs.x; ts[1] += ex * vs.y; ts[2] += ex * vs.z; ts[3] += ex * vs.w;
    td[0] += ex * vd.x; td[1] += ex * vd.y; td[2] += ex * vd.z; td[3] += ex * vd.w;
    tf[0] += ex * vf.x; tf[1] += ex * vf.y; tf[2] += ex * vf.z; tf[3] += ex * vf.w;
  }
  float inv = 1.f / den;
  #pragma unroll
  for (int hp = 0; hp < 4; hp++){
    float vs = ts[hp] * inv, vd = td[hp] * inv, vf = tf[hp] * inv;
    vs += __shfl_xor(vs, 1, 64); vs += __shfl_xor(vs, 2, 64);
    vd += __shfl_xor(vd, 1, 64); vd += __shfl_xor(vd, 2, 64);
    vf += __shfl_xor(vf, 1, 64); vf += __shfl_xor(vf, 2, 64);
    ts[hp] = vs; td[hp] = vd; tf[hp] = vf;
  }
  if (h == 0){
    const float* Pp = P + kb * PSTRIDE;
    long ob = abase + (long)node * 4;
    *(float4*)&aS2[ob] = make_float4(ts[0] + Pp[896], ts[1] + Pp[897], ts[2] + Pp[898], ts[3] + Pp[899]);
    *(float4*)&aD2[ob] = make_float4(td[0] + Pp[900], td[1] + Pp[901], td[2] + Pp[902], td[3] + Pp[903]);
    *(float4*)&gf2[ob] = make_float4(tf[0] + Pp[904], tf[1] + Pp[905], tf[2] + Pp[906], tf[3] + Pp[907]);
  }
}

// ---------------- layer-2 softmax + output stencil: thread per (node, L2-head h') ----------------
__global__ __launch_bounds__(256) void k_out(const void* x, const float* aS2, const float* aD2,
                                             const float* gf2, const float* P, void* out){
  __shared__ int s_flag;
  if (threadIdx.x < 64){ int f = detect_isf32(x); if (threadIdx.x == 0) s_flag = f; }
  __syncthreads();
  int isf32 = s_flag;
  int t = blockIdx.x * 256 + threadIdx.x;
  int node = t >> 2, hp = t & 3;
  if (node >= NPTS) return;
  int kb = blockIdx.y;
  long abase = (long)kb * SA;
  int cnt = g_cnt[kb];
  float adv = aD2[abase + (long)node * 4 + hp];

  float e[13]; int jc[13];
  float mx = -3e38f;
  #pragma unroll
  for (int tt = 0; tt < 13; tt++){
    int off = g_off[kb * 16 + tt];
    int j = node + off;
    bool ok = (tt < cnt) && ((unsigned)j < NPTS);
    int jj = j < 0 ? 0 : (j >= NPTS ? NPTS - 1 : j);
    jc[tt] = jj;
    float v = aS2[abase + (long)jj * 4 + hp] + adv;
    v = v > 0.f ? v : NEG * v;
    e[tt] = ok ? v : -3e38f;
    mx = fmaxf(mx, e[tt]);
  }
  float den = 0.f, sm = 0.f;
  #pragma unroll
  for (int tt = 0; tt < 13; tt++){
    float ex = expf(e[tt] - mx);
    den += ex;
    sm += ex * gf2[abase + (long)jc[tt] * 4 + hp];
  }
  float r = sm / den;
  r += __shfl_xor(r, 1, 64);
  r += __shfl_xor(r, 2, 64);
  if (hp == 0){
    float o = r + P[kb * PSTRIDE + 908];
    long oi = (long)kb * NPTS + node;
    if (isf32) ((float*)out)[oi] = o;
    else       ((u16*)out)[oi]  = f2bf(o);
  }
}

extern "C" void kernel_launch(void* const* d_in, const int* in_sizes, int n_in,
                              void* d_out, int out_size, void* d_ws, size_t ws_size,
                              hipStream_t stream){
  char* ws = (char*)d_ws;
  size_t off = 0;
  auto take = [&](size_t b) -> size_t { size_t r = off; off += (b + 255) & ~(size_t)255; return r; };

  float* aS1 = (float*)(ws + take((size_t)3 * SA * 4));
  float* aD1 = (float*)(ws + take((size_t)3 * SA * 4));
  float* gs  = (float*)(ws + take((size_t)3 * NPTS * 16 * 4));
  float* gd  = (float*)(ws + take((size_t)3 * NPTS * 16 * 4));
  float* gf  = (float*)(ws + take((size_t)3 * NPTS * 16 * 4));
  float* aS2 = (float*)(ws + take((size_t)3 * SA * 4));
  float* aD2 = (float*)(ws + take((size_t)3 * SA * 4));
  float* gf2 = (float*)(ws + take((size_t)3 * SA * 4));
  float* P   = (float*)(ws + take((size_t)3 * PSTRIDE * 4));

  const void* x   = d_in[0];
  const void* W1  = d_in[4];
  const void* a1s = d_in[5];
  const void* a1d = d_in[6];
  const void* b1  = d_in[7];
  const void* W2  = d_in[8];
  const void* a2s = d_in[9];
  const void* a2d = d_in[10];
  const void* b2  = d_in[11];
  const void* wfc = d_in[12];
  const void* bfc = d_in[13];

  k_folds<<<dim3(1, 3), 256, 0, stream>>>(x, W1, a1s, a1d, b1, W2, a2s, a2d, b2, wfc, bfc, P);
  k_feat<<<dim3((NPTS + 255) / 256, 3), 256, 0, stream>>>(x, P, aS1, aD1, gs, gd, gf);
  k_l2pre<<<dim3((SA + 255) / 256, 3), 256, 0, stream>>>(aS1, aD1, gs, gd, gf, P, aS2, aD2, gf2);
  k_out<<<dim3((SA + 255) / 256, 3), 256, 0, stream>>>(x, aS2, aD2, gf2, P, d_out);
}

// Round 5
// 73.131 us; speedup vs baseline: 15.2127x; 1.7447x over previous
//
#include <hip/hip_runtime.h>

#define NPTS 50000
#define NEG 0.2f
#define PSTRIDE 960
#define OUT_N 212          // output nodes per block
#define GRID_MAIN 236      // ceil(50000/212)
#define LSTR 257           // LDS row stride (floats)

typedef unsigned short u16;
typedef unsigned int   u32;

__device__ __forceinline__ float bf2f(u16 u){ return __uint_as_float(((u32)u) << 16); }
__device__ __forceinline__ u16 f2bf(float f){
  u32 w = __float_as_uint(f);
  return (u16)((w + 0x7fffu + ((w >> 16) & 1u)) >> 16);
}
__device__ __forceinline__ float ldraw(const void* p, long i, int isf32){
  return isf32 ? ((const float*)p)[i] : bf2f(((const u16*)p)[i]);
}
__device__ __forceinline__ float wred(float v){
  #pragma unroll
  for (int m = 32; m > 0; m >>= 1) v += __shfl_xor(v, m, 64);
  return v;
}

// wave-parallel dtype sniff on first 512 u16 of x (needs >= 64 threads)
__device__ int detect_isf32(const void* x){
  int lane = threadIdx.x & 63;
  const u16* p = (const u16*)x;
  int ze = 0, sane = 0;
  #pragma unroll
  for (int r = 0; r < 8; r++){
    int idx = lane * 8 + r;
    u16 u = p[idx];
    if ((idx & 1) == 0 && u == 0) ze++;
    float a = fabsf(bf2f(u));
    if (u == 0 || (a > 0.015625f && a < 64.f)) sane++;
  }
  #pragma unroll
  for (int m = 32; m > 0; m >>= 1){ ze += __shfl_xor(ze, m, 64); sane += __shfl_xor(sane, m, 64); }
  return (ze > 200) ? 1 : (sane > 460 ? 0 : 1);
}

template<int B> __device__ __forceinline__ int nbr_off(int t){
  if (B == 0){ constexpr int O[7]  = {0,-1,-3,-5,-7,-9,-11}; return O[t]; }
  else if (B == 1){ constexpr int O[7]  = {0,1,3,5,7,9,11}; return O[t]; }
  else { constexpr int O[13] = {0,-1,1,-3,3,-5,5,-7,7,-9,9,-11,11}; return O[t]; }
}

// ============ fold stage 1: sAg[kb][q][hp][m] = sum_{c' in head hp} W2[m,c']*vec_q[c'] ============
// grid (256, 3), 256 thr: block = row m, wave = hp, lane = c'
__global__ __launch_bounds__(256) void k_fold1(const void* x, const void* W2, const void* a2s,
                                               const void* a2d, const void* wfc, float* sAg){
  __shared__ int s_flag;
  if (threadIdx.x < 64){ int f = detect_isf32(x); if (threadIdx.x == 0) s_flag = f; }
  __syncthreads();
  int isf32 = s_flag;
  int kb = blockIdx.y, m = blockIdx.x;
  int hp = threadIdx.x >> 6, ch = threadIdx.x & 63;
  int c = hp * 64 + ch;
  float w = ldraw(W2, (long)kb * 65536 + (long)m * 256 + c, isf32);
  float s = wred(w * ldraw(a2s, kb * 256 + c, isf32));
  float d = wred(w * ldraw(a2d, kb * 256 + c, isf32));
  float f = wred(w * ldraw(wfc, kb * 64 + ch, isf32) * 0.25f);
  if (ch == 0){
    float* sA = sAg + (long)kb * 3072;
    sA[(0 * 4 + hp) * 256 + m] = s;
    sA[(1 * 4 + hp) * 256 + m] = d;
    sA[(2 * 4 + hp) * 256 + m] = f;
  }
}

// ============ fold stage 2: build P ============
// P[0:64) Ws1[k*4+h]; [64:128) Wd1; [128:384) Ws2[k*16+h*4+hp]; [384:640) Wd2; [640:896) Wf2
// [896+hp] c2s; [900+hp] c2d; [904+hp] c2f; [908] Cb
// grid (82, 3), 256 thr = 4 waves; wave-task id = blockIdx.x*4 + wave
__global__ __launch_bounds__(256) void k_fold2(const void* x, const void* W1, const void* a1s,
                                               const void* a1d, const void* b1, const void* b2,
                                               const void* wfc, const void* bfc,
                                               const float* sAg, float* P){
  __shared__ int s_flag;
  if (threadIdx.x < 64){ int f = detect_isf32(x); if (threadIdx.x == 0) s_flag = f; }
  __syncthreads();
  int isf32 = s_flag;
  int kb = blockIdx.y;
  int wid = blockIdx.x * 4 + (threadIdx.x >> 6);
  int ch = threadIdx.x & 63;
  float* Pp = P + kb * PSTRIDE;
  const float* sA = sAg + (long)kb * 3072;

  if (wid < 256){                       // Ws2/Wd2/Wf2[k][h][hp]
    int hp = wid & 3, h = (wid >> 2) & 3, k = wid >> 4;
    int m = h * 64 + ch;
    float w = ldraw(W1, (long)kb * 4096 + k * 256 + m, isf32);
    float s = wred(w * sA[(0 * 4 + hp) * 256 + m]);
    float d = wred(w * sA[(1 * 4 + hp) * 256 + m]);
    float f = wred(w * sA[(2 * 4 + hp) * 256 + m]);
    if (ch == 0){ Pp[128 + wid] = s; Pp[384 + wid] = d; Pp[640 + wid] = f; }
  } else if (wid < 320){                // Ws1/Wd1[k][h]
    int j = wid - 256; int h = j & 3, k = j >> 2;
    int c = h * 64 + ch;
    float w = ldraw(W1, (long)kb * 4096 + k * 256 + c, isf32);
    float s = wred(w * ldraw(a1s, kb * 256 + c, isf32));
    float d = wred(w * ldraw(a1d, kb * 256 + c, isf32));
    if (ch == 0){ Pp[j] = s; Pp[64 + j] = d; }
  } else if (wid < 324){                // biases c2s/c2d/c2f[hp]
    int hp = wid - 320;
    float a0 = 0.f, a1v = 0.f, a2v = 0.f;
    for (int it = 0; it < 4; it++){
      int m = it * 64 + ch;
      float bv = ldraw(b1, kb * 256 + m, isf32);
      a0  += bv * sA[(0 * 4 + hp) * 256 + m];
      a1v += bv * sA[(1 * 4 + hp) * 256 + m];
      a2v += bv * sA[(2 * 4 + hp) * 256 + m];
    }
    a0 = wred(a0); a1v = wred(a1v); a2v = wred(a2v);
    if (ch == 0){ Pp[896 + hp] = a0; Pp[900 + hp] = a1v; Pp[904 + hp] = a2v; }
  } else if (wid == 324){               // Cb
    float a = wred(ldraw(b2, kb * 64 + ch, isf32) * ldraw(wfc, kb * 64 + ch, isf32));
    if (ch == 0) Pp[908] = a + ldraw(bfc, kb, isf32);
  }
}

// ============ fused main: feats -> L1 softmax+stencil -> L2 softmax+stencil -> out ============
// block: 212 output nodes; phase A spans 256 nodes (+-22 halo), phase B 234 (+-11)
template<int BRANCH>
__global__ __launch_bounds__(256) void k_main(const void* x, const float* P, void* out){
  constexpr int CNT = (BRANCH == 2) ? 13 : 7;
  __shared__ float sP[912];
  __shared__ float fe8[8][LSTR];          // rows 0-3 aS1[h], 4-7 aD1[h]
  __shared__ float feG[4][LSTR][12];      // [h][slot][gs0..3, gd0..3, gf0..3]
  __shared__ float o2[12][LSTR];          // rows 0-3 aS2[hp], 4-7 aD2[hp], 8-11 gf2[hp]
  __shared__ int s_flag;
  int tid = threadIdx.x;
  if (tid < 64){ int f = detect_isf32(x); if (tid == 0) s_flag = f; }
  for (int i = tid; i < 912; i += 256) sP[i] = P[BRANCH * PSTRIDE + i];
  __syncthreads();
  int isf32 = s_flag;
  int base = blockIdx.x * OUT_N;

  // ---- phase A: per-node projections into LDS ----
  {
    int g = base - 22 + tid;
    bool vA = (unsigned)g < NPTS;
    float xv[16];
    if (vA){
      if (isf32){
        const float4* xp = (const float4*)x + (long)g * 4;
        #pragma unroll
        for (int q = 0; q < 4; q++){
          float4 v = xp[q];
          xv[q*4] = v.x; xv[q*4+1] = v.y; xv[q*4+2] = v.z; xv[q*4+3] = v.w;
        }
      } else {
        const uint4* xp = (const uint4*)x + (long)g * 2;
        #pragma unroll
        for (int q = 0; q < 2; q++){
          uint4 v = xp[q];
          u32 wsv[4] = {v.x, v.y, v.z, v.w};
          #pragma unroll
          for (int r = 0; r < 4; r++){
            xv[q*8 + r*2]     = bf2f((u16)(wsv[r] & 0xffffu));
            xv[q*8 + r*2 + 1] = bf2f((u16)(wsv[r] >> 16));
          }
        }
      }
    } else {
      #pragma unroll
      for (int k = 0; k < 16; k++) xv[k] = 0.f;
    }
    float s1[4] = {0,0,0,0}, d1[4] = {0,0,0,0};
    float s2[16], d2[16], f2[16];
    #pragma unroll
    for (int t = 0; t < 16; t++){ s2[t] = 0.f; d2[t] = 0.f; f2[t] = 0.f; }
    #pragma unroll
    for (int k = 0; k < 16; k++){
      float xk = xv[k];
      float4 a = *(const float4*)&sP[k * 4];
      s1[0] += xk * a.x; s1[1] += xk * a.y; s1[2] += xk * a.z; s1[3] += xk * a.w;
      float4 b = *(const float4*)&sP[64 + k * 4];
      d1[0] += xk * b.x; d1[1] += xk * b.y; d1[2] += xk * b.z; d1[3] += xk * b.w;
      #pragma unroll
      for (int q = 0; q < 4; q++){
        float4 vs = *(const float4*)&sP[128 + k * 16 + q * 4];
        s2[q*4] += xk * vs.x; s2[q*4+1] += xk * vs.y; s2[q*4+2] += xk * vs.z; s2[q*4+3] += xk * vs.w;
        float4 vd = *(const float4*)&sP[384 + k * 16 + q * 4];
        d2[q*4] += xk * vd.x; d2[q*4+1] += xk * vd.y; d2[q*4+2] += xk * vd.z; d2[q*4+3] += xk * vd.w;
        float4 vf = *(const float4*)&sP[640 + k * 16 + q * 4];
        f2[q*4] += xk * vf.x; f2[q*4+1] += xk * vf.y; f2[q*4+2] += xk * vf.z; f2[q*4+3] += xk * vf.w;
      }
    }
    #pragma unroll
    for (int h = 0; h < 4; h++){ fe8[h][tid] = s1[h]; fe8[4 + h][tid] = d1[h]; }
    #pragma unroll
    for (int h = 0; h < 4; h++){
      *(float4*)&feG[h][tid][0] = make_float4(s2[h*4], s2[h*4+1], s2[h*4+2], s2[h*4+3]);
      *(float4*)&feG[h][tid][4] = make_float4(d2[h*4], d2[h*4+1], d2[h*4+2], d2[h*4+3]);
      *(float4*)&feG[h][tid][8] = make_float4(f2[h*4], f2[h*4+1], f2[h*4+2], f2[h*4+3]);
    }
  }
  __syncthreads();

  // ---- phase B: L1 softmax + stencil; thread per (node,h); quad-shfl over h ----
  for (int pass = 0; pass < 4; pass++){
    int task = pass * 256 + tid;
    if (task < 234 * 4){
      int slotB = task >> 2, h = task & 3;
      int gB = base - 11 + slotB;
      bool vB = (unsigned)gB < NPTS;
      float ts[4] = {0,0,0,0}, td[4] = {0,0,0,0}, tf[4] = {0,0,0,0};
      if (vB){
        int sAs = slotB + 11;
        float adv = fe8[4 + h][sAs];
        float e[CNT]; int sa[CNT];
        float mx = -3e38f;
        #pragma unroll
        for (int tt = 0; tt < CNT; tt++){
          int off = nbr_off<BRANCH>(tt);
          int j = gB + off;
          sa[tt] = sAs + off;
          float v = fe8[h][sa[tt]] + adv;
          v = v > 0.f ? v : NEG * v;
          e[tt] = ((unsigned)j < NPTS) ? v : -3e38f;
          mx = fmaxf(mx, e[tt]);
        }
        float den = 0.f;
        #pragma unroll
        for (int tt = 0; tt < CNT; tt++){
          float ex = expf(e[tt] - mx);
          den += ex;
          const float* gp = &feG[h][sa[tt]][0];
          float4 vs = *(const float4*)(gp);
          float4 vd = *(const float4*)(gp + 4);
          float4 vf = *(const float4*)(gp + 8);
          ts[0] += ex * vs.x; ts[1] += ex * vs.y; ts[2] += ex * vs.z; ts[3] += ex * vs.w;
          td[0] += ex * vd.x; td[1] += ex * vd.y; td[2] += ex * vd.z; td[3] += ex * vd.w;
          tf[0] += ex * vf.x; tf[1] += ex * vf.y; tf[2] += ex * vf.z; tf[3] += ex * vf.w;
        }
        float inv = 1.f / den;
        #pragma unroll
        for (int hp = 0; hp < 4; hp++){ ts[hp] *= inv; td[hp] *= inv; tf[hp] *= inv; }
      }
      #pragma unroll
      for (int hp = 0; hp < 4; hp++){
        ts[hp] += __shfl_xor(ts[hp], 1, 64); ts[hp] += __shfl_xor(ts[hp], 2, 64);
        td[hp] += __shfl_xor(td[hp], 1, 64); td[hp] += __shfl_xor(td[hp], 2, 64);
        tf[hp] += __shfl_xor(tf[hp], 1, 64); tf[hp] += __shfl_xor(tf[hp], 2, 64);
      }
      if (h == 0){
        #pragma unroll
        for (int hp = 0; hp < 4; hp++){
          o2[hp][slotB]     = vB ? ts[hp] + sP[896 + hp] : 0.f;
          o2[4 + hp][slotB] = vB ? td[hp] + sP[900 + hp] : 0.f;
          o2[8 + hp][slotB] = vB ? tf[hp] + sP[904 + hp] : 0.f;
        }
      }
    }
  }
  __syncthreads();

  // ---- phase C: L2 softmax + stencil -> output; thread per (node,hp) ----
  for (int pass = 0; pass < 4; pass++){
    int task = pass * 256 + tid;
    if (task < OUT_N * 4){
      int offn = task >> 2, hp = task & 3;
      int i = base + offn;
      bool vC = i < NPTS;
      float r = 0.f;
      if (vC){
        int sBs = offn + 11;
        float adv = o2[4 + hp][sBs];
        float e[CNT]; int sb[CNT];
        float mx = -3e38f;
        #pragma unroll
        for (int tt = 0; tt < CNT; tt++){
          int off = nbr_off<BRANCH>(tt);
          int j = i + off;
          sb[tt] = sBs + off;
          float v = o2[hp][sb[tt]] + adv;
          v = v > 0.f ? v : NEG * v;
          e[tt] = ((unsigned)j < NPTS) ? v : -3e38f;
          mx = fmaxf(mx, e[tt]);
        }
        float den = 0.f, sm = 0.f;
        #pragma unroll
        for (int tt = 0; tt < CNT; tt++){
          float ex = expf(e[tt] - mx);
          den += ex;
          sm += ex * o2[8 + hp][sb[tt]];
        }
        r = sm / den;
      }
      r += __shfl_xor(r, 1, 64);
      r += __shfl_xor(r, 2, 64);
      if (hp == 0 && vC){
        float o = r + sP[908];
        long oi = (long)BRANCH * NPTS + i;
        if (isf32) ((float*)out)[oi] = o;
        else       ((u16*)out)[oi]  = f2bf(o);
      }
    }
  }
}

extern "C" void kernel_launch(void* const* d_in, const int* in_sizes, int n_in,
                              void* d_out, int out_size, void* d_ws, size_t ws_size,
                              hipStream_t stream){
  char* ws = (char*)d_ws;
  size_t off = 0;
  auto take = [&](size_t b) -> size_t { size_t r = off; off += (b + 255) & ~(size_t)255; return r; };

  float* sAg = (float*)(ws + take((size_t)3 * 3 * 4 * 256 * 4));
  float* P   = (float*)(ws + take((size_t)3 * PSTRIDE * 4));

  const void* x   = d_in[0];
  const void* W1  = d_in[4];
  const void* a1s = d_in[5];
  const void* a1d = d_in[6];
  const void* b1  = d_in[7];
  const void* W2  = d_in[8];
  const void* a2s = d_in[9];
  const void* a2d = d_in[10];
  const void* b2  = d_in[11];
  const void* wfc = d_in[12];
  const void* bfc = d_in[13];

  k_fold1<<<dim3(256, 3), 256, 0, stream>>>(x, W2, a2s, a2d, wfc, sAg);
  k_fold2<<<dim3(82, 3), 256, 0, stream>>>(x, W1, a1s, a1d, b1, b2, wfc, bfc, sAg, P);
  k_main<0><<<GRID_MAIN, 256, 0, stream>>>(x, P, d_out);
  k_main<1><<<GRID_MAIN, 256, 0, stream>>>(x, P, d_out);
  k_main<2><<<GRID_MAIN, 256, 0, stream>>>(x, P, d_out);
}

// Round 6
// 64.138 us; speedup vs baseline: 17.3458x; 1.1402x over previous
//
#include <hip/hip_runtime.h>

#define NPTS 50000
#define NEG 0.2f
#define PSTRIDE 960
#define OUT_N 196            // output nodes per block
#define SPAN_A 240           // OUT_N + 44 (phase-A halo)
#define SPAN_B 218           // OUT_N + 22 (phase-B halo)
#define STRA 240             // LDS row stride; 240 mod 32 == 16 -> 2-way banks
#define LOG2E 1.44269504088896340736f

typedef unsigned short u16;
typedef unsigned int   u32;

__device__ __forceinline__ float bf2f(u16 u){ return __uint_as_float(((u32)u) << 16); }
__device__ __forceinline__ u16 f2bf(float f){
  u32 w = __float_as_uint(f);
  return (u16)((w + 0x7fffu + ((w >> 16) & 1u)) >> 16);
}
__device__ __forceinline__ u32 pk2(float a, float b){
  return (u32)f2bf(a) | ((u32)f2bf(b) << 16);
}
__device__ __forceinline__ float ldraw(const void* p, long i, int isf32){
  return isf32 ? ((const float*)p)[i] : bf2f(((const u16*)p)[i]);
}
__device__ __forceinline__ float wred(float v){
  #pragma unroll
  for (int m = 32; m > 0; m >>= 1) v += __shfl_xor(v, m, 64);
  return v;
}

__device__ int detect_isf32(const void* x){
  int lane = threadIdx.x & 63;
  const u16* p = (const u16*)x;
  int ze = 0, sane = 0;
  #pragma unroll
  for (int r = 0; r < 8; r++){
    int idx = lane * 8 + r;
    u16 u = p[idx];
    if ((idx & 1) == 0 && u == 0) ze++;
    float a = fabsf(bf2f(u));
    if (u == 0 || (a > 0.015625f && a < 64.f)) sane++;
  }
  #pragma unroll
  for (int m = 32; m > 0; m >>= 1){ ze += __shfl_xor(ze, m, 64); sane += __shfl_xor(sane, m, 64); }
  return (ze > 200) ? 1 : (sane > 460 ? 0 : 1);
}

template<int B> __device__ __forceinline__ int nbr_off(int t){
  if (B == 0){ constexpr int O[7]  = {0,-1,-3,-5,-7,-9,-11}; return O[t]; }
  else if (B == 1){ constexpr int O[7]  = {0,1,3,5,7,9,11}; return O[t]; }
  else { constexpr int O[13] = {0,-1,1,-3,3,-5,5,-7,7,-9,9,-11,11}; return O[t]; }
}

// ============ fold stage 1 ============
__global__ __launch_bounds__(256) void k_fold1(const void* x, const void* W2, const void* a2s,
                                               const void* a2d, const void* wfc, float* sAg){
  __shared__ int s_flag;
  if (threadIdx.x < 64){ int f = detect_isf32(x); if (threadIdx.x == 0) s_flag = f; }
  __syncthreads();
  int isf32 = s_flag;
  int kb = blockIdx.y, m = blockIdx.x;
  int hp = threadIdx.x >> 6, ch = threadIdx.x & 63;
  int c = hp * 64 + ch;
  float w = ldraw(W2, (long)kb * 65536 + (long)m * 256 + c, isf32);
  float s = wred(w * ldraw(a2s, kb * 256 + c, isf32));
  float d = wred(w * ldraw(a2d, kb * 256 + c, isf32));
  float f = wred(w * ldraw(wfc, kb * 64 + ch, isf32) * 0.25f);
  if (ch == 0){
    float* sA = sAg + (long)kb * 3072;
    sA[(0 * 4 + hp) * 256 + m] = s;
    sA[(1 * 4 + hp) * 256 + m] = d;
    sA[(2 * 4 + hp) * 256 + m] = f;
  }
}

// ============ fold stage 2 ============
__global__ __launch_bounds__(256) void k_fold2(const void* x, const void* W1, const void* a1s,
                                               const void* a1d, const void* b1, const void* b2,
                                               const void* wfc, const void* bfc,
                                               const float* sAg, float* P){
  __shared__ int s_flag;
  if (threadIdx.x < 64){ int f = detect_isf32(x); if (threadIdx.x == 0) s_flag = f; }
  __syncthreads();
  int isf32 = s_flag;
  int kb = blockIdx.y;
  int wid = blockIdx.x * 4 + (threadIdx.x >> 6);
  int ch = threadIdx.x & 63;
  float* Pp = P + kb * PSTRIDE;
  const float* sA = sAg + (long)kb * 3072;

  if (wid < 256){
    int hp = wid & 3, h = (wid >> 2) & 3, k = wid >> 4;
    int m = h * 64 + ch;
    float w = ldraw(W1, (long)kb * 4096 + k * 256 + m, isf32);
    float s = wred(w * sA[(0 * 4 + hp) * 256 + m]);
    float d = wred(w * sA[(1 * 4 + hp) * 256 + m]);
    float f = wred(w * sA[(2 * 4 + hp) * 256 + m]);
    if (ch == 0){ Pp[128 + wid] = s; Pp[384 + wid] = d; Pp[640 + wid] = f; }
  } else if (wid < 320){
    int j = wid - 256; int h = j & 3, k = j >> 2;
    int c = h * 64 + ch;
    float w = ldraw(W1, (long)kb * 4096 + k * 256 + c, isf32);
    float s = wred(w * ldraw(a1s, kb * 256 + c, isf32));
    float d = wred(w * ldraw(a1d, kb * 256 + c, isf32));
    if (ch == 0){ Pp[j] = s; Pp[64 + j] = d; }
  } else if (wid < 324){
    int hp = wid - 320;
    float a0 = 0.f, a1v = 0.f, a2v = 0.f;
    for (int it = 0; it < 4; it++){
      int m = it * 64 + ch;
      float bv = ldraw(b1, kb * 256 + m, isf32);
      a0  += bv * sA[(0 * 4 + hp) * 256 + m];
      a1v += bv * sA[(1 * 4 + hp) * 256 + m];
      a2v += bv * sA[(2 * 4 + hp) * 256 + m];
    }
    a0 = wred(a0); a1v = wred(a1v); a2v = wred(a2v);
    if (ch == 0){ Pp[896 + hp] = a0; Pp[900 + hp] = a1v; Pp[904 + hp] = a2v; }
  } else if (wid == 324){
    float a = wred(ldraw(b2, kb * 64 + ch, isf32) * ldraw(wfc, kb * 64 + ch, isf32));
    if (ch == 0) Pp[908] = a + ldraw(bfc, kb, isf32);
  }
}

// ============ fused main ============
template<int BRANCH>
__device__ __forceinline__ void run_main(const void* x, void* out, int isf32, int base,
                                         float (&sP)[912], float (&fe8)[8][STRA],
                                         u32 (&feG)[4][STRA][7], float (&o2)[12][STRA]){
  constexpr int CNT = (BRANCH == 2) ? 13 : 7;
  int tid = threadIdx.x;

  // ---- phase A: project x -> 8 f32 + 48 bf16 features per node ----
  if (tid < SPAN_A){
    int g = base - 22 + tid;
    bool vA = (unsigned)g < NPTS;
    float xv[16];
    if (vA){
      if (isf32){
        const float4* xp = (const float4*)x + (long)g * 4;
        #pragma unroll
        for (int q = 0; q < 4; q++){
          float4 v = xp[q];
          xv[q*4] = v.x; xv[q*4+1] = v.y; xv[q*4+2] = v.z; xv[q*4+3] = v.w;
        }
      } else {
        const uint4* xp = (const uint4*)x + (long)g * 2;
        #pragma unroll
        for (int q = 0; q < 2; q++){
          uint4 v = xp[q];
          u32 wsv[4] = {v.x, v.y, v.z, v.w};
          #pragma unroll
          for (int r = 0; r < 4; r++){
            xv[q*8 + r*2]     = bf2f((u16)(wsv[r] & 0xffffu));
            xv[q*8 + r*2 + 1] = bf2f((u16)(wsv[r] >> 16));
          }
        }
      }
    } else {
      #pragma unroll
      for (int k = 0; k < 16; k++) xv[k] = 0.f;
    }
    float s1[4] = {0,0,0,0}, d1[4] = {0,0,0,0};
    float s2[16], d2[16], f2[16];
    #pragma unroll
    for (int t = 0; t < 16; t++){ s2[t] = 0.f; d2[t] = 0.f; f2[t] = 0.f; }
    #pragma unroll
    for (int k = 0; k < 16; k++){
      float xk = xv[k];
      float4 a = *(const float4*)&sP[k * 4];
      s1[0] += xk * a.x; s1[1] += xk * a.y; s1[2] += xk * a.z; s1[3] += xk * a.w;
      float4 b = *(const float4*)&sP[64 + k * 4];
      d1[0] += xk * b.x; d1[1] += xk * b.y; d1[2] += xk * b.z; d1[3] += xk * b.w;
      #pragma unroll
      for (int q = 0; q < 4; q++){
        float4 vs = *(const float4*)&sP[128 + k * 16 + q * 4];
        s2[q*4] += xk * vs.x; s2[q*4+1] += xk * vs.y; s2[q*4+2] += xk * vs.z; s2[q*4+3] += xk * vs.w;
        float4 vd = *(const float4*)&sP[384 + k * 16 + q * 4];
        d2[q*4] += xk * vd.x; d2[q*4+1] += xk * vd.y; d2[q*4+2] += xk * vd.z; d2[q*4+3] += xk * vd.w;
        float4 vf = *(const float4*)&sP[640 + k * 16 + q * 4];
        f2[q*4] += xk * vf.x; f2[q*4+1] += xk * vf.y; f2[q*4+2] += xk * vf.z; f2[q*4+3] += xk * vf.w;
      }
    }
    #pragma unroll
    for (int h = 0; h < 4; h++){
      fe8[h][tid] = s1[h] * LOG2E;      // pre-scaled logit parts
      fe8[4 + h][tid] = d1[h] * LOG2E;
      feG[h][tid][0] = pk2(s2[h*4+0], s2[h*4+1]);
      feG[h][tid][1] = pk2(s2[h*4+2], s2[h*4+3]);
      feG[h][tid][2] = pk2(d2[h*4+0], d2[h*4+1]);
      feG[h][tid][3] = pk2(d2[h*4+2], d2[h*4+3]);
      feG[h][tid][4] = pk2(f2[h*4+0], f2[h*4+1]);
      feG[h][tid][5] = pk2(f2[h*4+2], f2[h*4+3]);
    }
  }
  __syncthreads();

  // ---- phase B: L1 softmax + stencil; thread per (slot,h); quad-reduce over h ----
  #pragma unroll
  for (int pass = 0; pass < 4; pass++){
    int task = pass * 256 + tid;
    if (task < SPAN_B * 4){
      int slotB = task >> 2, h = task & 3;
      int gB = base - 11 + slotB;
      bool vB = (unsigned)gB < NPTS;
      float ts[4] = {0,0,0,0}, td[4] = {0,0,0,0}, tf[4] = {0,0,0,0};
      if (vB){
        int sAs = slotB + 11;
        float adv = fe8[4 + h][sAs];
        float e[CNT]; int sa[CNT];
        float mx = -3e38f;
        #pragma unroll
        for (int tt = 0; tt < CNT; tt++){
          int off = nbr_off<BRANCH>(tt);
          int j = gB + off;
          sa[tt] = sAs + off;
          float v = fe8[h][sa[tt]] + adv;        // already *LOG2E
          v = v > 0.f ? v : NEG * v;
          e[tt] = ((unsigned)j < NPTS) ? v : -3e38f;
          mx = fmaxf(mx, e[tt]);
        }
        float den = 0.f;
        #pragma unroll
        for (int tt = 0; tt < CNT; tt++){
          float ex = exp2f(e[tt] - mx);
          den += ex;
          const u32* gp = &feG[h][sa[tt]][0];
          u32 g0 = gp[0], g1 = gp[1], g2 = gp[2], g3 = gp[3], g4 = gp[4], g5 = gp[5];
          ts[0] += ex * bf2f((u16)(g0 & 0xffffu)); ts[1] += ex * bf2f((u16)(g0 >> 16));
          ts[2] += ex * bf2f((u16)(g1 & 0xffffu)); ts[3] += ex * bf2f((u16)(g1 >> 16));
          td[0] += ex * bf2f((u16)(g2 & 0xffffu)); td[1] += ex * bf2f((u16)(g2 >> 16));
          td[2] += ex * bf2f((u16)(g3 & 0xffffu)); td[3] += ex * bf2f((u16)(g3 >> 16));
          tf[0] += ex * bf2f((u16)(g4 & 0xffffu)); tf[1] += ex * bf2f((u16)(g4 >> 16));
          tf[2] += ex * bf2f((u16)(g5 & 0xffffu)); tf[3] += ex * bf2f((u16)(g5 >> 16));
        }
        float inv = 1.f / den;
        #pragma unroll
        for (int hp = 0; hp < 4; hp++){ ts[hp] *= inv; td[hp] *= inv; tf[hp] *= inv; }
      }
      #pragma unroll
      for (int hp = 0; hp < 4; hp++){
        ts[hp] += __shfl_xor(ts[hp], 1, 64); ts[hp] += __shfl_xor(ts[hp], 2, 64);
        td[hp] += __shfl_xor(td[hp], 1, 64); td[hp] += __shfl_xor(td[hp], 2, 64);
        tf[hp] += __shfl_xor(tf[hp], 1, 64); tf[hp] += __shfl_xor(tf[hp], 2, 64);
      }
      if (h == 0){
        #pragma unroll
        for (int hp = 0; hp < 4; hp++){
          o2[hp][slotB]     = vB ? (ts[hp] + sP[896 + hp]) * LOG2E : 0.f;
          o2[4 + hp][slotB] = vB ? (td[hp] + sP[900 + hp]) * LOG2E : 0.f;
          o2[8 + hp][slotB] = vB ? tf[hp] + sP[904 + hp] : 0.f;
        }
      }
    }
  }
  __syncthreads();

  // ---- phase C: L2 softmax + stencil -> out; thread per (node,hp) ----
  #pragma unroll
  for (int pass = 0; pass < 4; pass++){
    int task = pass * 256 + tid;
    if (task < OUT_N * 4){
      int offn = task >> 2, hp = task & 3;
      int i = base + offn;
      bool vC = i < NPTS;
      float r = 0.f;
      if (vC){
        int sBs = offn + 11;
        float adv = o2[4 + hp][sBs];
        float e[CNT]; int sb[CNT];
        float mx = -3e38f;
        #pragma unroll
        for (int tt = 0; tt < CNT; tt++){
          int off = nbr_off<BRANCH>(tt);
          int j = i + off;
          sb[tt] = sBs + off;
          float v = o2[hp][sb[tt]] + adv;        // already *LOG2E
          v = v > 0.f ? v : NEG * v;
          e[tt] = ((unsigned)j < NPTS) ? v : -3e38f;
          mx = fmaxf(mx, e[tt]);
        }
        float den = 0.f, sm = 0.f;
        #pragma unroll
        for (int tt = 0; tt < CNT; tt++){
          float ex = exp2f(e[tt] - mx);
          den += ex;
          sm += ex * o2[8 + hp][sb[tt]];
        }
        r = sm / den;
      }
      r += __shfl_xor(r, 1, 64);
      r += __shfl_xor(r, 2, 64);
      if (hp == 0 && vC){
        float o = r + sP[908];
        long oi = (long)BRANCH * NPTS + i;
        if (isf32) ((float*)out)[oi] = o;
        else       ((u16*)out)[oi]  = f2bf(o);
      }
    }
  }
}

__global__ __launch_bounds__(256) void k_main(const void* x, const float* P, void* out){
  __shared__ float sP[912];
  __shared__ float fe8[8][STRA];
  __shared__ u32 feG[4][STRA][7];
  __shared__ float o2[12][STRA];
  __shared__ int s_flag;
  int tid = threadIdx.x;
  int br = blockIdx.y;
  if (tid < 64){ int f = detect_isf32(x); if (tid == 0) s_flag = f; }
  for (int i = tid; i < 912; i += 256) sP[i] = P[br * PSTRIDE + i];
  __syncthreads();
  int isf32 = s_flag;
  int base = blockIdx.x * OUT_N;
  if (br == 0)      run_main<0>(x, out, isf32, base, sP, fe8, feG, o2);
  else if (br == 1) run_main<1>(x, out, isf32, base, sP, fe8, feG, o2);
  else              run_main<2>(x, out, isf32, base, sP, fe8, feG, o2);
}

extern "C" void kernel_launch(void* const* d_in, const int* in_sizes, int n_in,
                              void* d_out, int out_size, void* d_ws, size_t ws_size,
                              hipStream_t stream){
  char* ws = (char*)d_ws;
  size_t off = 0;
  auto take = [&](size_t b) -> size_t { size_t r = off; off += (b + 255) & ~(size_t)255; return r; };

  float* sAg = (float*)(ws + take((size_t)3 * 3072 * 4));
  float* P   = (float*)(ws + take((size_t)3 * PSTRIDE * 4));

  const void* x   = d_in[0];
  const void* W1  = d_in[4];
  const void* a1s = d_in[5];
  const void* a1d = d_in[6];
  const void* b1  = d_in[7];
  const void* W2  = d_in[8];
  const void* a2s = d_in[9];
  const void* a2d = d_in[10];
  const void* b2  = d_in[11];
  const void* wfc = d_in[12];
  const void* bfc = d_in[13];

  k_fold1<<<dim3(256, 3), 256, 0, stream>>>(x, W2, a2s, a2d, wfc, sAg);
  k_fold2<<<dim3(82, 3), 256, 0, stream>>>(x, W1, a1s, a1d, b1, b2, wfc, bfc, sAg, P);
  k_main<<<dim3((NPTS + OUT_N - 1) / OUT_N, 3), 256, 0, stream>>>(x, P, d_out);
}

// Round 7
// 58.935 us; speedup vs baseline: 18.8770x; 1.0883x over previous
//
#include <hip/hip_runtime.h>

#define NPTS 50000
#define NEG 0.2f
#define PSTRIDE 960
#define OUT_N 64             // k_AB output nodes per block
#define SPAN 86              // OUT_N + 22 (phase-A halo = stencil reach 11 both sides)
#define SP 87                // LDS slot stride (odd)
#define LOG2E 1.44269504088896340736f

typedef unsigned short u16;
typedef unsigned int   u32;

__device__ __forceinline__ float bf2f(u16 u){ return __uint_as_float(((u32)u) << 16); }
__device__ __forceinline__ u16 f2bf(float f){
  u32 w = __float_as_uint(f);
  return (u16)((w + 0x7fffu + ((w >> 16) & 1u)) >> 16);
}
__device__ __forceinline__ u32 pk2(float a, float b){
  return (u32)f2bf(a) | ((u32)f2bf(b) << 16);
}
__device__ __forceinline__ float ldraw(const void* p, long i, int isf32){
  return isf32 ? ((const float*)p)[i] : bf2f(((const u16*)p)[i]);
}
__device__ __forceinline__ float wred(float v){
  #pragma unroll
  for (int m = 32; m > 0; m >>= 1) v += __shfl_xor(v, m, 64);
  return v;
}

__device__ int detect_isf32(const void* x){
  int lane = threadIdx.x & 63;
  const u16* p = (const u16*)x;
  int ze = 0, sane = 0;
  #pragma unroll
  for (int r = 0; r < 8; r++){
    int idx = lane * 8 + r;
    u16 u = p[idx];
    if ((idx & 1) == 0 && u == 0) ze++;
    float a = fabsf(bf2f(u));
    if (u == 0 || (a > 0.015625f && a < 64.f)) sane++;
  }
  #pragma unroll
  for (int m = 32; m > 0; m >>= 1){ ze += __shfl_xor(ze, m, 64); sane += __shfl_xor(sane, m, 64); }
  return (ze > 200) ? 1 : (sane > 460 ? 0 : 1);
}

template<int B> __device__ __forceinline__ int nbr_off(int t){
  if (B == 0){ constexpr int O[7]  = {0,-1,-3,-5,-7,-9,-11}; return O[t]; }
  else if (B == 1){ constexpr int O[7]  = {0,1,3,5,7,9,11}; return O[t]; }
  else { constexpr int O[13] = {0,-1,1,-3,3,-5,5,-7,7,-9,9,-11,11}; return O[t]; }
}

// ============ fold stage 1 (also publishes dtype flag) ============
__global__ __launch_bounds__(256) void k_fold1(const void* x, const void* W2, const void* a2s,
                                               const void* a2d, const void* wfc, float* sAg,
                                               int* flag){
  __shared__ int s_flag;
  if (threadIdx.x < 64){ int f = detect_isf32(x); if (threadIdx.x == 0) s_flag = f; }
  __syncthreads();
  int isf32 = s_flag;
  if (blockIdx.x == 0 && blockIdx.y == 0 && threadIdx.x == 0) *flag = isf32;
  int kb = blockIdx.y, m = blockIdx.x;
  int hp = threadIdx.x >> 6, ch = threadIdx.x & 63;
  int c = hp * 64 + ch;
  float w = ldraw(W2, (long)kb * 65536 + (long)m * 256 + c, isf32);
  float s = wred(w * ldraw(a2s, kb * 256 + c, isf32));
  float d = wred(w * ldraw(a2d, kb * 256 + c, isf32));
  float f = wred(w * ldraw(wfc, kb * 64 + ch, isf32) * 0.25f);
  if (ch == 0){
    float* sA = sAg + (long)kb * 3072;
    sA[(0 * 4 + hp) * 256 + m] = s;
    sA[(1 * 4 + hp) * 256 + m] = d;
    sA[(2 * 4 + hp) * 256 + m] = f;
  }
}

// ============ fold stage 2 ============
__global__ __launch_bounds__(256) void k_fold2(const void* x, const void* W1, const void* a1s,
                                               const void* a1d, const void* b1, const void* b2,
                                               const void* wfc, const void* bfc,
                                               const float* sAg, float* P){
  __shared__ int s_flag;
  if (threadIdx.x < 64){ int f = detect_isf32(x); if (threadIdx.x == 0) s_flag = f; }
  __syncthreads();
  int isf32 = s_flag;
  int kb = blockIdx.y;
  int wid = blockIdx.x * 4 + (threadIdx.x >> 6);
  int ch = threadIdx.x & 63;
  float* Pp = P + kb * PSTRIDE;
  const float* sA = sAg + (long)kb * 3072;

  if (wid < 256){
    int hp = wid & 3, h = (wid >> 2) & 3, k = wid >> 4;
    int m = h * 64 + ch;
    float w = ldraw(W1, (long)kb * 4096 + k * 256 + m, isf32);
    float s = wred(w * sA[(0 * 4 + hp) * 256 + m]);
    float d = wred(w * sA[(1 * 4 + hp) * 256 + m]);
    float f = wred(w * sA[(2 * 4 + hp) * 256 + m]);
    if (ch == 0){ Pp[128 + wid] = s; Pp[384 + wid] = d; Pp[640 + wid] = f; }
  } else if (wid < 320){
    int j = wid - 256; int h = j & 3, k = j >> 2;
    int c = h * 64 + ch;
    float w = ldraw(W1, (long)kb * 4096 + k * 256 + c, isf32);
    float s = wred(w * ldraw(a1s, kb * 256 + c, isf32));
    float d = wred(w * ldraw(a1d, kb * 256 + c, isf32));
    if (ch == 0){ Pp[j] = s; Pp[64 + j] = d; }
  } else if (wid < 324){
    int hp = wid - 320;
    float a0 = 0.f, a1v = 0.f, a2v = 0.f;
    for (int it = 0; it < 4; it++){
      int m = it * 64 + ch;
      float bv = ldraw(b1, kb * 256 + m, isf32);
      a0  += bv * sA[(0 * 4 + hp) * 256 + m];
      a1v += bv * sA[(1 * 4 + hp) * 256 + m];
      a2v += bv * sA[(2 * 4 + hp) * 256 + m];
    }
    a0 = wred(a0); a1v = wred(a1v); a2v = wred(a2v);
    if (ch == 0){ Pp[896 + hp] = a0; Pp[900 + hp] = a1v; Pp[904 + hp] = a2v; }
  } else if (wid == 324){
    float a = wred(ldraw(b2, kb * 64 + ch, isf32) * ldraw(wfc, kb * 64 + ch, isf32));
    if (ch == 0) Pp[908] = a + ldraw(bfc, kb, isf32);
  }
}

// ============ phases A+B: feats (LDS) -> L1 softmax+stencil -> o2 (global) ============
template<int BRANCH>
__device__ __forceinline__ void run_ab(const void* x, const float* Pp, int isf32, int base,
                                       float (&fe8)[8][SP], u32 (&feG)[4][SP * 7], float* o2b){
  constexpr int CNT = (BRANCH == 2) ? 13 : 7;
  int tid = threadIdx.x;

  // ---- phase A ----
  if (tid < SPAN){
    int g = base - 11 + tid;
    bool vA = (unsigned)g < NPTS;
    float xv[16];
    if (vA){
      if (isf32){
        const float4* xp = (const float4*)x + (long)g * 4;
        #pragma unroll
        for (int q = 0; q < 4; q++){
          float4 v = xp[q];
          xv[q*4] = v.x; xv[q*4+1] = v.y; xv[q*4+2] = v.z; xv[q*4+3] = v.w;
        }
      } else {
        const uint4* xp = (const uint4*)x + (long)g * 2;
        #pragma unroll
        for (int q = 0; q < 2; q++){
          uint4 v = xp[q];
          u32 wsv[4] = {v.x, v.y, v.z, v.w};
          #pragma unroll
          for (int r = 0; r < 4; r++){
            xv[q*8 + r*2]     = bf2f((u16)(wsv[r] & 0xffffu));
            xv[q*8 + r*2 + 1] = bf2f((u16)(wsv[r] >> 16));
          }
        }
      }
    } else {
      #pragma unroll
      for (int k = 0; k < 16; k++) xv[k] = 0.f;
    }
    float s1[4] = {0,0,0,0}, d1[4] = {0,0,0,0};
    float s2[16], d2[16], f2[16];
    #pragma unroll
    for (int t = 0; t < 16; t++){ s2[t] = 0.f; d2[t] = 0.f; f2[t] = 0.f; }
    #pragma unroll
    for (int k = 0; k < 16; k++){
      float xk = xv[k];
      #pragma unroll
      for (int h = 0; h < 4; h++){
        s1[h] += xk * Pp[     k*4 + h];
        d1[h] += xk * Pp[64 + k*4 + h];
      }
      #pragma unroll
      for (int t = 0; t < 16; t++){
        s2[t] += xk * Pp[128 + k*16 + t];
        d2[t] += xk * Pp[384 + k*16 + t];
        f2[t] += xk * Pp[640 + k*16 + t];
      }
    }
    #pragma unroll
    for (int h = 0; h < 4; h++){
      fe8[h][tid]     = s1[h] * LOG2E;
      fe8[4 + h][tid] = d1[h] * LOG2E;
      u32* gp = &feG[h][tid * 7];
      gp[0] = pk2(s2[h*4+0], s2[h*4+1]);
      gp[1] = pk2(s2[h*4+2], s2[h*4+3]);
      gp[2] = pk2(d2[h*4+0], d2[h*4+1]);
      gp[3] = pk2(d2[h*4+2], d2[h*4+3]);
      gp[4] = pk2(f2[h*4+0], f2[h*4+1]);
      gp[5] = pk2(f2[h*4+2], f2[h*4+3]);
    }
  }
  __syncthreads();

  // ---- phase B: task per (node,h); 2 passes of 128 ----
  #pragma unroll
  for (int pass = 0; pass < 2; pass++){
    int task = pass * 128 + tid;
    int noff = task >> 2, h = task & 3;
    int i = base + noff;
    bool vB = i < NPTS;
    float ts[4] = {0,0,0,0}, td[4] = {0,0,0,0}, tf[4] = {0,0,0,0};
    if (vB){
      int sAs = noff + 11;
      float adv = fe8[4 + h][sAs];
      float e[CNT]; int sa[CNT];
      float mx = -3e38f;
      #pragma unroll
      for (int tt = 0; tt < CNT; tt++){
        int off = nbr_off<BRANCH>(tt);
        int j = i + off;
        sa[tt] = sAs + off;
        float v = fe8[h][sa[tt]] + adv;
        v = v > 0.f ? v : NEG * v;
        e[tt] = ((unsigned)j < NPTS) ? v : -3e38f;
        mx = fmaxf(mx, e[tt]);
      }
      float den = 0.f;
      #pragma unroll
      for (int tt = 0; tt < CNT; tt++){
        float ex = exp2f(e[tt] - mx);
        den += ex;
        const u32* gp = &feG[h][sa[tt] * 7];
        u32 g0 = gp[0], g1 = gp[1], g2 = gp[2], g3 = gp[3], g4 = gp[4], g5 = gp[5];
        ts[0] += ex * bf2f((u16)(g0 & 0xffffu)); ts[1] += ex * bf2f((u16)(g0 >> 16));
        ts[2] += ex * bf2f((u16)(g1 & 0xffffu)); ts[3] += ex * bf2f((u16)(g1 >> 16));
        td[0] += ex * bf2f((u16)(g2 & 0xffffu)); td[1] += ex * bf2f((u16)(g2 >> 16));
        td[2] += ex * bf2f((u16)(g3 & 0xffffu)); td[3] += ex * bf2f((u16)(g3 >> 16));
        tf[0] += ex * bf2f((u16)(g4 & 0xffffu)); tf[1] += ex * bf2f((u16)(g4 >> 16));
        tf[2] += ex * bf2f((u16)(g5 & 0xffffu)); tf[3] += ex * bf2f((u16)(g5 >> 16));
      }
      float inv = 1.f / den;
      #pragma unroll
      for (int hp = 0; hp < 4; hp++){ ts[hp] *= inv; td[hp] *= inv; tf[hp] *= inv; }
    }
    #pragma unroll
    for (int hp = 0; hp < 4; hp++){
      ts[hp] += __shfl_xor(ts[hp], 1, 64); ts[hp] += __shfl_xor(ts[hp], 2, 64);
      td[hp] += __shfl_xor(td[hp], 1, 64); td[hp] += __shfl_xor(td[hp], 2, 64);
      tf[hp] += __shfl_xor(tf[hp], 1, 64); tf[hp] += __shfl_xor(tf[hp], 2, 64);
    }
    if (h == 0 && vB){
      float* ob = o2b + (long)i * 12;
      *(float4*)(ob + 0) = make_float4((ts[0] + Pp[896]) * LOG2E, (ts[1] + Pp[897]) * LOG2E,
                                       (ts[2] + Pp[898]) * LOG2E, (ts[3] + Pp[899]) * LOG2E);
      *(float4*)(ob + 4) = make_float4((td[0] + Pp[900]) * LOG2E, (td[1] + Pp[901]) * LOG2E,
                                       (td[2] + Pp[902]) * LOG2E, (td[3] + Pp[903]) * LOG2E);
      *(float4*)(ob + 8) = make_float4(tf[0] + Pp[904], tf[1] + Pp[905],
                                       tf[2] + Pp[906], tf[3] + Pp[907]);
    }
  }
}

__global__ __launch_bounds__(128) void k_AB(const void* x, const float* P, const int* flag,
                                            float* o2g){
  __shared__ float fe8[8][SP];
  __shared__ u32 feG[4][SP * 7];
  int br = blockIdx.y;
  int isf32 = *flag;
  const float* Pp = P + br * PSTRIDE;
  float* o2b = o2g + (long)br * NPTS * 12;
  int base = blockIdx.x * OUT_N;
  if (br == 0)      run_ab<0>(x, Pp, isf32, base, fe8, feG, o2b);
  else if (br == 1) run_ab<1>(x, Pp, isf32, base, fe8, feG, o2b);
  else              run_ab<2>(x, Pp, isf32, base, fe8, feG, o2b);
}

// ============ phase C: L2 softmax + stencil -> out (no LDS, no barriers) ============
template<int BRANCH>
__device__ __forceinline__ void run_c(const float* ob, const float* Pp, int isf32, long t,
                                      void* out){
  constexpr int CNT = (BRANCH == 2) ? 13 : 7;
  int node = (int)(t >> 2), hp = (int)(t & 3);
  if (node >= NPTS) return;
  float adv = ob[(long)node * 12 + 4 + hp];
  float e[CNT]; int jc[CNT];
  float mx = -3e38f;
  #pragma unroll
  for (int tt = 0; tt < CNT; tt++){
    int off = nbr_off<BRANCH>(tt);
    int j = node + off;
    int jj = j < 0 ? 0 : (j >= NPTS ? NPTS - 1 : j);
    jc[tt] = jj;
    float v = ob[(long)jj * 12 + hp] + adv;
    v = v > 0.f ? v : NEG * v;
    e[tt] = ((unsigned)j < NPTS) ? v : -3e38f;
    mx = fmaxf(mx, e[tt]);
  }
  float den = 0.f, sm = 0.f;
  #pragma unroll
  for (int tt = 0; tt < CNT; tt++){
    float ex = exp2f(e[tt] - mx);
    den += ex;
    sm += ex * ob[(long)jc[tt] * 12 + 8 + hp];
  }
  float r = sm / den;
  r += __shfl_xor(r, 1, 64);
  r += __shfl_xor(r, 2, 64);
  if (hp == 0){
    float o = r + Pp[908];
    long oi = (long)BRANCH * NPTS + node;
    if (isf32) ((float*)out)[oi] = o;
    else       ((u16*)out)[oi]  = f2bf(o);
  }
}

__global__ __launch_bounds__(256) void k_C(const float* o2g, const float* P, const int* flag,
                                           void* out){
  long t = (long)blockIdx.x * 256 + threadIdx.x;
  int br = blockIdx.y;
  int isf32 = *flag;
  const float* ob = o2g + (long)br * NPTS * 12;
  const float* Pp = P + br * PSTRIDE;
  if (br == 0)      run_c<0>(ob, Pp, isf32, t, out);
  else if (br == 1) run_c<1>(ob, Pp, isf32, t, out);
  else              run_c<2>(ob, Pp, isf32, t, out);
}

extern "C" void kernel_launch(void* const* d_in, const int* in_sizes, int n_in,
                              void* d_out, int out_size, void* d_ws, size_t ws_size,
                              hipStream_t stream){
  char* ws = (char*)d_ws;
  size_t off = 0;
  auto take = [&](size_t b) -> size_t { size_t r = off; off += (b + 255) & ~(size_t)255; return r; };

  float* sAg  = (float*)(ws + take((size_t)3 * 3072 * 4));
  float* P    = (float*)(ws + take((size_t)3 * PSTRIDE * 4));
  int*   flag = (int*)(ws + take(4));
  float* o2g  = (float*)(ws + take((size_t)3 * NPTS * 12 * 4));

  const void* x   = d_in[0];
  const void* W1  = d_in[4];
  const void* a1s = d_in[5];
  const void* a1d = d_in[6];
  const void* b1  = d_in[7];
  const void* W2  = d_in[8];
  const void* a2s = d_in[9];
  const void* a2d = d_in[10];
  const void* b2  = d_in[11];
  const void* wfc = d_in[12];
  const void* bfc = d_in[13];

  k_fold1<<<dim3(256, 3), 256, 0, stream>>>(x, W2, a2s, a2d, wfc, sAg, flag);
  k_fold2<<<dim3(82, 3), 256, 0, stream>>>(x, W1, a1s, a1d, b1, b2, wfc, bfc, sAg, P);
  k_AB<<<dim3((NPTS + OUT_N - 1) / OUT_N, 3), 128, 0, stream>>>(x, P, flag, o2g);
  k_C<<<dim3((NPTS * 4 + 255) / 256, 3), 256, 0, stream>>>(o2g, P, flag, d_out);
}